// Round 9
// baseline (360.741 us; speedup 1.0000x reference)
//
#include <hip/hip_runtime.h>
#include <hip/hip_bf16.h>

typedef float f32x4 __attribute__((ext_vector_type(4)));
typedef int   i32x4 __attribute__((ext_vector_type(4)));
typedef __bf16 bf16x8 __attribute__((ext_vector_type(8)));
typedef unsigned short u16;
typedef unsigned short u16x4 __attribute__((ext_vector_type(4)));
typedef unsigned short u16x8 __attribute__((ext_vector_type(8)));

#define MAXE 32

// fp32 -> bf16 native RNE cvt (compiler emits v_cvt_pk_bf16_f32)
__device__ __forceinline__ u16 f2bf(float f) {
  __bf16 h = (__bf16)f;
  return __builtin_bit_cast(u16, h);
}

// inp fp32 -> bf16 pre-pass (~10 us)
__global__ __launch_bounds__(256)
void cvt_bf16(const float* __restrict__ in, u16* __restrict__ out, int n8) {
  int i = blockIdx.x * 256 + threadIdx.x;
  if (i < n8) {
    f32x4 a = *(const f32x4*)(in + (long long)i * 8);
    f32x4 b = *(const f32x4*)(in + (long long)i * 8 + 4);
    u16x8 r = { f2bf(a[0]), f2bf(a[1]), f2bf(a[2]), f2bf(a[3]),
                f2bf(b[0]), f2bf(b[1]), f2bf(b[2]), f2bf(b[3]) };
    *(u16x8*)(out + (long long)i * 8) = r;
  }
}

// shared expert-prefix lookup: batched loads + predicated register walk
__device__ __forceinline__ int expert_lookup(const int* counts, int E, int bm,
                                             int mt_in, int& row0, int& cnt, int& mt) {
  int cs[MAXE];
#pragma unroll
  for (int j = 0; j < MAXE / 4; ++j) {
    if (j * 4 + 3 < E) *(i32x4*)&cs[j * 4] = *(const i32x4*)(counts + j * 4);
    else {
#pragma unroll
      for (int q = 0; q < 4; ++q) cs[j*4+q] = (j*4+q < E) ? counts[j*4+q] : 0;
    }
  }
  int e = -1; row0 = 0; cnt = 0; mt = mt_in;
#pragma unroll
  for (int i = 0; i < MAXE; ++i) {
    if (i < E && e < 0) {
      int ntl = (cs[i] + bm - 1) / bm;
      if (mt < ntl) { e = i; cnt = cs[i]; }
      else { mt -= ntl; row0 += cs[i]; }
    }
  }
  return e;
}

// ============ GEMM1: BM=512 x BN=128, BK=32, 8 waves, single-touch w1 ============
// r8 model: co-resident blocks stall in lockstep; G1's per-step B loads are
// HBM-cold (~1000cy exposed) and 8 sequential blocks/CU x 32 cold steps = 264us.
// Fix: 512-row blocks -> 512 working blocks (2/CU, ONE round), each w1 byte
// touched by exactly one block, 4.2 MFLOP/step (1242cy matrix) hides latency.
// Template = r3's proven reg-staged + XOR-swizzled bf16 LDS + 2-deep pipeline.
#define B1M 512
#define B1N 128
#define B1K 32
#define N1T 512

__global__ __launch_bounds__(N1T, 2)
void ffn_gemm1(const u16* __restrict__ Ain, const float* __restrict__ Bw,
               const float* __restrict__ bias, u16* __restrict__ Out,
               const int* __restrict__ counts, int E, int T, int N, int K)
{
  int row0, cnt, mt;
  int e = expert_lookup(counts, E, B1M, blockIdx.y, row0, cnt, mt);
  if (e < 0) return;
  int valid = cnt - mt * B1M; if (valid > B1M) valid = B1M;
  row0 += mt * B1M;
  const int n0 = blockIdx.x * B1N;

  const float* Be = Bw + (long long)e * N * K;
  const float* be = bias + (long long)e * N;

  __shared__ u16 As[2][B1M][B1K];   // 32 KB per buf
  __shared__ u16 Bs[2][B1N][B1K];   // 8 KB per buf   -> 80 KB total, 2 blk/CU

  const int t = threadIdx.x;
  const int lane = t & 63;
  const int w = t >> 6, wr = w >> 1, wc = w & 1;   // 4M x 2N waves -> 128x64 each
  const int NKT = K / B1K;                          // 32

  // A: 4 shots of u16x8 per thread (512 rows x 64B)
  long long offA[4];
  int aRow[4], aCol[4];
#pragma unroll
  for (int i = 0; i < 4; ++i) {
    int c = i * N1T + t;
    aRow[i] = c >> 2; aCol[i] = (c & 3) << 3;
    int gr = row0 + aRow[i]; if (gr > T - 1) gr = T - 1;
    offA[i] = (long long)gr * K + aCol[i];
  }
  // B: 2 shots of f32x4 per thread (128 rows x 128B)
  long long offB[2];
  int bRow[2], bCol[2];
#pragma unroll
  for (int i = 0; i < 2; ++i) {
    int c = i * N1T + t;
    bRow[i] = c >> 3; bCol[i] = (c & 7) << 2;
    offB[i] = (long long)(n0 + bRow[i]) * K + bCol[i];
  }

  f32x4 acc[8][4];
#pragma unroll
  for (int i = 0; i < 8; ++i)
#pragma unroll
    for (int j = 0; j < 4; ++j) acc[i][j] = (f32x4){0.f, 0.f, 0.f, 0.f};

  u16x8 rAu[4]; float rB[8];

  auto load_g = [&](int kt) {
    const int k0 = kt * B1K;
#pragma unroll
    for (int i = 0; i < 4; ++i)
      rAu[i] = *(const u16x8*)(Ain + offA[i] + k0);
#pragma unroll
    for (int i = 0; i < 2; ++i) {
      f32x4 v = *(const f32x4*)(Be + offB[i] + k0);
      rB[i*4+0] = v[0]; rB[i*4+1] = v[1]; rB[i*4+2] = v[2]; rB[i*4+3] = v[3];
    }
  };

  // XOR-swizzle on 16B granules (r3-proven, 0 conflicts): phys = kg ^ ((row>>1)&3)
  auto store_tile = [&](int buf) {
#pragma unroll
    for (int i = 0; i < 4; ++i) {
      int row = aRow[i], col = aCol[i];
      int kg = (col >> 3) ^ ((row >> 1) & 3);
      *(u16x8*)&As[buf][row][kg * 8] = rAu[i];
    }
#pragma unroll
    for (int i = 0; i < 2; ++i) {
      int row = bRow[i], col = bCol[i];
      int kg = (col >> 3) ^ ((row >> 1) & 3);
      int off = kg * 8 + ((col >> 2) & 1) * 4;
      u16x4 pk = { f2bf(rB[i*4+0]), f2bf(rB[i*4+1]), f2bf(rB[i*4+2]), f2bf(rB[i*4+3]) };
      *(u16x4*)&Bs[buf][row][off] = pk;
    }
  };

  load_g(0);
  store_tile(0);
  load_g(1);
  __syncthreads();

  const int rl = lane & 15;
  const int kgf = (lane >> 4) ^ ((rl >> 1) & 3);

  for (int kt = 0; kt < NKT; ++kt) {
    const int cur = kt & 1;

    bf16x8 af[8], bfr[4];
#pragma unroll
    for (int nf = 0; nf < 4; ++nf)
      bfr[nf] = __builtin_bit_cast(bf16x8, *(const u16x8*)&Bs[cur][wc*64 + nf*16 + rl][kgf*8]);
#pragma unroll
    for (int mf = 0; mf < 8; ++mf)
      af[mf] = __builtin_bit_cast(bf16x8, *(const u16x8*)&As[cur][wr*128 + mf*16 + rl][kgf*8]);

    if (kt + 1 < NKT) store_tile(cur ^ 1);
    if (kt + 2 < NKT) load_g(kt + 2);

    __builtin_amdgcn_s_setprio(1);
#pragma unroll
    for (int mf = 0; mf < 8; ++mf)
#pragma unroll
      for (int nf = 0; nf < 4; ++nf)
        acc[mf][nf] = __builtin_amdgcn_mfma_f32_16x16x32_bf16(af[mf], bfr[nf], acc[mf][nf], 0, 0, 0);
    __builtin_amdgcn_s_setprio(0);

    if (kt + 1 < NKT) __syncthreads();
  }

  // epilogue: C/D col=lane&15, row=(lane>>4)*4+r [m89/m91]
  const int cl = lane & 15, rg = lane >> 4;
#pragma unroll
  for (int nf = 0; nf < 4; ++nf) {
    int gcol = n0 + wc * 64 + nf * 16 + cl;
    float bv = be[gcol];
#pragma unroll
    for (int mf = 0; mf < 8; ++mf) {
#pragma unroll
      for (int r = 0; r < 4; ++r) {
        int lrow = wr * 128 + mf * 16 + rg * 4 + r;
        if (lrow < valid) {
          float v = acc[mf][nf][r] + bv;
          v = 0.5f * v * (1.0f + erff(v * 0.70710678118654752f));
          Out[(long long)(row0 + lrow) * N + gcol] = f2bf(v);
        }
      }
    }
  }
}

// ============ GEMM2: r3 reg-staged 128x128 template (proven ~859 TF) ============
#define BM 128
#define BN 128
#define BK 32
#define NT 256

template<bool DO_GELU, bool OUT_BF16>
__global__ __launch_bounds__(NT)
void ffn_gemm(const u16* __restrict__ Ain, const float* __restrict__ Bw,
              const float* __restrict__ bias, void* __restrict__ Out,
              const int* __restrict__ counts, int E, int T, int N, int K)
{
  int row0, cnt, mt;
  int e = expert_lookup(counts, E, BM, blockIdx.y, row0, cnt, mt);
  if (e < 0) return;
  int valid = cnt - mt * BM; if (valid > BM) valid = BM;
  row0 += mt * BM;
  const int n0 = blockIdx.x * BN;

  const float* Be = Bw + (long long)e * N * K;
  const float* be = bias + (long long)e * N;

  __shared__ u16 As[2][BM][BK];
  __shared__ u16 Bs[2][BN][BK];

  const int t = threadIdx.x;
  const int lane = t & 63;
  const int w = t >> 6, wr = w >> 1, wc = w & 1;
  const int NKT = K / BK;

  long long offA[2];
#pragma unroll
  for (int i = 0; i < 2; ++i) {
    int c = i * NT + t;
    int row = c >> 2, col = (c & 3) << 3;
    int gr = row0 + row; if (gr > T - 1) gr = T - 1;
    offA[i] = (long long)gr * K + col;
  }
  long long offB[4];
#pragma unroll
  for (int i = 0; i < 4; ++i) {
    int c = i * NT + t;
    offB[i] = (long long)(n0 + (c >> 3)) * K + ((c & 7) << 2);
  }

  f32x4 acc[4][4];
#pragma unroll
  for (int i = 0; i < 4; ++i)
#pragma unroll
    for (int j = 0; j < 4; ++j) acc[i][j] = (f32x4){0.f, 0.f, 0.f, 0.f};

  u16x8 rAu[2]; float rB[16];

  auto load_g = [&](int kt) {
    const int k0 = kt * BK;
#pragma unroll
    for (int i = 0; i < 2; ++i)
      rAu[i] = *(const u16x8*)(Ain + offA[i] + k0);
#pragma unroll
    for (int i = 0; i < 4; ++i) {
      f32x4 v = *(const f32x4*)(Be + offB[i] + k0);
      rB[i*4+0] = v[0]; rB[i*4+1] = v[1]; rB[i*4+2] = v[2]; rB[i*4+3] = v[3];
    }
  };

  auto store_tile = [&](int buf) {
#pragma unroll
    for (int i = 0; i < 2; ++i) {
      int c = i * NT + t;
      int row = c >> 2, col = (c & 3) << 3;
      int kg2 = (col >> 3) ^ ((row >> 1) & 3);
      *(u16x8*)&As[buf][row][kg2 * 8] = rAu[i];
    }
#pragma unroll
    for (int i = 0; i < 4; ++i) {
      int c = i * NT + t;
      int row = c >> 3, col = (c & 7) << 2;
      int kg2 = (col >> 3) ^ ((row >> 1) & 3);
      int off = kg2 * 8 + ((col >> 2) & 1) * 4;
      u16x4 pk = { f2bf(rB[i*4+0]), f2bf(rB[i*4+1]), f2bf(rB[i*4+2]), f2bf(rB[i*4+3]) };
      *(u16x4*)&Bs[buf][row][off] = pk;
    }
  };

  load_g(0);
  store_tile(0);
  load_g(1);
  __syncthreads();

  const int rl = lane & 15;
  const int kgf = (lane >> 4) ^ ((rl >> 1) & 3);

  for (int kt = 0; kt < NKT; ++kt) {
    const int cur = kt & 1;

    bf16x8 af[4], bfr[4];
#pragma unroll
    for (int mf = 0; mf < 4; ++mf)
      af[mf] = __builtin_bit_cast(bf16x8, *(const u16x8*)&As[cur][wr*64 + mf*16 + rl][kgf*8]);
#pragma unroll
    for (int nf = 0; nf < 4; ++nf)
      bfr[nf] = __builtin_bit_cast(bf16x8, *(const u16x8*)&Bs[cur][wc*64 + nf*16 + rl][kgf*8]);

    if (kt + 1 < NKT) store_tile(cur ^ 1);
    if (kt + 2 < NKT) load_g(kt + 2);

#pragma unroll
    for (int mf = 0; mf < 4; ++mf)
#pragma unroll
      for (int nf = 0; nf < 4; ++nf)
        acc[mf][nf] = __builtin_amdgcn_mfma_f32_16x16x32_bf16(af[mf], bfr[nf], acc[mf][nf], 0, 0, 0);

    if (kt + 1 < NKT) __syncthreads();
  }

  const int cl = lane & 15, rg = lane >> 4;
#pragma unroll
  for (int mf = 0; mf < 4; ++mf) {
#pragma unroll
    for (int nf = 0; nf < 4; ++nf) {
      int gcol = n0 + wc*64 + nf*16 + cl;
      float bv = be[gcol];
#pragma unroll
      for (int r = 0; r < 4; ++r) {
        int lrow = wr*64 + mf*16 + rg*4 + r;
        if (lrow < valid) {
          float v = acc[mf][nf][r] + bv;
          if constexpr (DO_GELU)
            v = 0.5f * v * (1.0f + erff(v * 0.70710678118654752f));
          long long idx = (long long)(row0 + lrow) * N + gcol;
          if constexpr (OUT_BF16) ((u16*)Out)[idx] = f2bf(v);
          else                    ((float*)Out)[idx] = v;
        }
      }
    }
  }
}

extern "C" void kernel_launch(void* const* d_in, const int* in_sizes, int n_in,
                              void* d_out, int out_size, void* d_ws, size_t ws_size,
                              hipStream_t stream) {
  const float* inp = (const float*)d_in[0];
  const float* w1  = (const float*)d_in[1];
  const float* b1  = (const float*)d_in[2];
  const float* w2  = (const float*)d_in[3];
  const float* b2  = (const float*)d_in[4];
  const int* cnts  = (const int*)d_in[5];

  const int E = in_sizes[5];
  const int H = in_sizes[2] / E;       // 4096
  const int D = in_sizes[4] / E;       // 1024
  const int T = in_sizes[0] / D;       // 8192

  u16* hbuf = (u16*)d_ws;                                  // T*H bf16 (64 MB)
  u16* ibuf = (u16*)((char*)d_ws + (size_t)T * H * 2);     // T*D bf16 (16 MB)

  // 0) inp -> bf16
  const int n8 = (T * D) / 8;
  cvt_bf16<<<dim3((n8 + 255) / 256), dim3(256), 0, stream>>>(inp, ibuf, n8);

  // 1) h = gelu(ibuf @ w1^T + b1) — 512-row blocks, grid 32 x 32 (512 working)
  const int tiles1 = T / B1M + E;
  dim3 g1(H / B1N, tiles1);
  ffn_gemm1<<<g1, dim3(N1T), 0, stream>>>(ibuf, w1, b1, hbuf, cnts, E, T, H, D);

  // 2) out = hbuf @ w2^T + b2 — proven r3 template, grid 8 x 80
  const int tiles2 = T / BM + E;
  dim3 g2(D / BN, tiles2);
  ffn_gemm<false, false><<<g2, dim3(NT), 0, stream>>>(
      hbuf, w2, b2, d_out, cnts, E, T, D, H);
}